// Round 2
// 1690.572 us; speedup vs baseline: 1.1164x; 1.1164x over previous
//
#include <hip/hip_runtime.h>
#include <cstddef>

#define LOG2E 1.4426950408889634f
#define LN2   0.6931471805599453f

typedef float    f32x2 __attribute__((ext_vector_type(2)));
typedef float    f32x4 __attribute__((ext_vector_type(4)));
typedef _Float16 half8 __attribute__((ext_vector_type(8)));

constexpr int K_    = 256;
constexpr int T_    = 2048;
constexpr int DMAX_ = 64;
constexpr int B_    = 16;

__device__ __forceinline__ float fexp2(float x) { return __builtin_amdgcn_exp2f(x); }
__device__ __forceinline__ float flog2(float x) { return __builtin_amdgcn_logf(x); }
__device__ __forceinline__ float frcp (float x) { return __builtin_amdgcn_rcpf(x); }

// cross-half (lane ^ 32) exchange on the VALU via v_permlane32_swap_b32.
// Hardened: two DISTINCT "=&v" outputs, movs inside the asm (no coalescing
// possible), s_nop for the VALU->permlane read hazard.
// Returns {r.x, r.y} = the pair {lo-half value, hi-half value} in an order
// fixed by HW convention; r.x + r.y is the cross-half sum either way, and
// the "other half's value" is whichever of r.x/r.y differs from own.
__device__ __forceinline__ f32x2 xchg32(float x) {
    float a, b;
    asm("v_mov_b32 %0, %2\n\t"
        "v_mov_b32 %1, %2\n\t"
        "s_nop 1\n\t"
        "v_permlane32_swap_b32 %0, %1"
        : "=&v"(a), "=&v"(b)
        : "v"(x));
    return (f32x2){a, b};
}

// max-reduce across a 16-lane row via DPP row_ror (VALU, no LDS pipe).
template<int CTRL>
__device__ __forceinline__ float dpp_maxf(float x) {
    int m = __builtin_amdgcn_update_dpp(0, __builtin_bit_cast(int, x), CTRL, 0xF, 0xF, true);
    return fmaxf(x, __builtin_bit_cast(float, m));
}

// 512 threads = 8 waves, pinned 2 waves/SIMD. Wave w owns columns 32w..32w+31.
// Lane map: j = 32w + (lane&31); q = lane>>5 owns duration ages 32q+1..32q+32.
//   -> MFMA output tile column (lane&15) lands in its consuming lane:
//      mySmv = (lane&16) ? d1.x : d0.x  (no bpermute)
//   -> cross-half exchanges are lane^32 = v_permlane32_swap_b32 (no LDS swizzle)
// Barrier: lgkmcnt(0) + raw s_barrier, BRACKETED by sched_barrier(0) so no LDS
// op can be scheduler-hoisted across it (rule-#18 analog). Global prefetch
// (depth-3 ring) and the alpha store stay in flight across barriers (no
// vmcnt(0) drain per step).
// exp2/log2 cancellation: p = S*ea^2, nv0 = Smv*ga^2 (ea/ga computed off-chain).
__global__ __launch_bounds__(512)
__attribute__((amdgpu_waves_per_eu(2, 2)))
void hsmm_fwd_kernel(const float* __restrict__ logB,   // [B,T,K]
                     const float* __restrict__ pi,     // [K]
                     const float* __restrict__ A,      // [K,K]
                     const float* __restrict__ D,      // [K,DMAX]
                     float* __restrict__ out)          // [16] loglik ++ [B,T,K] alphas
{
    const int b    = blockIdx.x;
    const int tid  = threadIdx.x;
    const int w    = tid >> 6;
    const int lane = tid & 63;
    const int j    = (w << 5) | (lane & 31);   // column 0..255
    const int q    = lane >> 5;                // age half

    alignas(16) __shared__ _Float16 lds_ph[2][K_];    // p f16, ping-pong by t&1
    alignas(16) __shared__ float    lds_red[2][8];    // per-wave max a_in, ping-pong

    // ---- init: B-fragments (P = exp(A_logits), f16, MFMA B-layout) ----
    half8 Bf0[8], Bf1[8];
    {
        const int krow = (lane >> 4) * 8;
        const int n0   = (w << 5) + (lane & 15);
        #pragma unroll
        for (int kc = 0; kc < 8; ++kc) {
            #pragma unroll
            for (int jj = 0; jj < 8; ++jj) {
                const int k = kc * 32 + krow + jj;
                Bf0[kc][jj] = (_Float16)fexp2(A[(size_t)k * K_ + n0     ] * LOG2E);
                Bf1[kc][jj] = (_Float16)fexp2(A[(size_t)k * K_ + n0 + 16] * LOG2E);
            }
        }
    }
    f32x2 pDf[16];   // ages 32q+2k+1 (.x), 32q+2k+2 (.y)
    {
        const float* Dj = D + (size_t)j * DMAX_ + 32 * q;
        #pragma unroll
        for (int k = 0; k < 16; ++k)
            pDf[k] = (f32x2){ fexp2(Dj[2 * k] * LOG2E), fexp2(Dj[2 * k + 1] * LOG2E) };
    }

    f32x2 v[16];
    #pragma unroll
    for (int k = 0; k < 16; ++k) v[k] = (f32x2){0.0f, 0.0f};
    if (q == 0) v[0].x = 1.0f;          // age-1 holds pi (anchor = pi)
    float mcol     = pi[j] * LOG2E;     // column anchor (base-2)
    float cumb     = 0.0f;
    float m_anchor = 0.0f;              // lag-2 block anchor

    if (tid < 8) { lds_red[0][tid] = 0.0f; lds_red[1][tid] = 0.0f; }
    __syncthreads();

    const float* lb = logB + (size_t)b * T_ * K_ + j;
    float*       ao = out + 16 + (size_t)b * T_ * K_ + j;

    // depth-3 prefetch ring for the per-step emission
    float bld0 = lb[0];
    float bld1 = lb[K_];
    float bld2 = lb[2 * K_];
    int   ldoff = 3 * K_;
    int   aoff  = 0;

    #pragma unroll 2
    for (int t = 0; t < T_; ++t) {
        const int s = t & 1;
        cumb = fmaf(bld0, LOG2E, cumb);

        // off-chain scale factors (overlap the FMA tree below):
        //   ea^2 = exp2(cumb+mcol-m_anchor), ga^2 = exp2(-(...)); half-arg + clamp
        const float argh = 0.5f * (cumb + mcol - m_anchor);
        const float ea   = fminf(fexp2(argh),  1.8e19f);
        const float ga   = fminf(fexp2(-argh), 1.8e19f);
        const float mac  = m_anchor - cumb;   // for the exact-log mcol update later

        // ---- phase A: duration sum (16 pk_fma) + 1 permlane cross-half ----
        f32x2 s0 = {0.f,0.f}, s1 = {0.f,0.f}, s2 = {0.f,0.f}, s3 = {0.f,0.f};
        #pragma unroll
        for (int k = 0; k < 16; k += 4) {
            s0 = __builtin_elementwise_fma(v[k + 0], pDf[k + 0], s0);
            s1 = __builtin_elementwise_fma(v[k + 1], pDf[k + 1], s1);
            s2 = __builtin_elementwise_fma(v[k + 2], pDf[k + 2], s2);
            s3 = __builtin_elementwise_fma(v[k + 3], pDf[k + 3], s3);
        }
        f32x2 sp = (s0 + s1) + (s2 + s3);
        float Sl = sp.x + sp.y;
        f32x2 pr = xchg32(Sl);
        float S  = pr.x + pr.y;                 // full sum, direction-agnostic

        // p = exp2(alpha - m_anchor) = S * ea^2   (log2->exp2 cancelled)
        float p = fminf(S * ea * ea, 60000.0f); // f16-overflow clamp
        if (q == 0) lds_ph[s][j] = (_Float16)p;
        float alpha_l2 = cumb + mcol + flog2(S);   // only feeds the global store

        // ---- the ONE barrier: pinned so no LDS op crosses it ----
        asm volatile("s_waitcnt lgkmcnt(0)" ::: "memory");
        __builtin_amdgcn_sched_barrier(0);
        __builtin_amdgcn_s_barrier();
        __builtin_amdgcn_sched_barrier(0);

        // prefetch t+3 (stays in flight across barriers) + alpha store (lazy drain)
        bld0 = bld1; bld1 = bld2;
        bld2 = lb[ldoff];
        ldoff += (ldoff < (T_ - 1) * K_) ? K_ : 0;
        if (q == 0) ao[aoff] = alpha_l2 * LN2;
        aoff += K_;

        // hoisted anchor-feed read (other ping-pong buffer; latency overlaps MFMA)
        f32x4 r0 = ((const f32x4*)lds_red[s ^ 1])[0];
        f32x4 r1 = ((const f32x4*)lds_red[s ^ 1])[1];

        // ---- phase B: MFMA matvec, 4 independent 4-deep chains ----
        const _Float16* pb = lds_ph[s];
        const int fo = (lane >> 4) * 8;
        const f32x4 z = {0.f,0.f,0.f,0.f};
        f32x4 d0a = z, d0b = z, d1a = z, d1b = z;
        #pragma unroll
        for (int kc = 0; kc < 4; ++kc) {
            half8 af = *(const half8*)(pb + kc * 32 + fo);
            d0a = __builtin_amdgcn_mfma_f32_16x16x32_f16(af, Bf0[kc], d0a, 0, 0, 0);
            d1a = __builtin_amdgcn_mfma_f32_16x16x32_f16(af, Bf1[kc], d1a, 0, 0, 0);
        }
        #pragma unroll
        for (int kc = 4; kc < 8; ++kc) {
            half8 af = *(const half8*)(pb + kc * 32 + fo);
            d0b = __builtin_amdgcn_mfma_f32_16x16x32_f16(af, Bf0[kc], d0b, 0, 0, 0);
            d1b = __builtin_amdgcn_mfma_f32_16x16x32_f16(af, Bf1[kc], d1b, 0, 0, 0);
        }
        float sva = d0a.x + d0b.x;              // Smv[32w + (lane&15)]
        float svb = d1a.x + d1b.x;              // Smv[32w + 16 + (lane&15)]
        float mySmv = (lane & 16) ? svb : sva;  // own column — no bpermute

        float m_next = fmaxf(fmaxf(fmaxf(r0.x, r0.y), fmaxf(r0.z, r0.w)),
                             fmaxf(fmaxf(r1.x, r1.y), fmaxf(r1.z, r1.w)));

        // anchor feed (off-chain): wave max of 16 distinct values via DPP row_ror
        float mx = fmaxf(sva, svb);
        mx = dpp_maxf<0x121>(mx);   // ror:1
        mx = dpp_maxf<0x122>(mx);   // ror:2
        mx = dpp_maxf<0x124>(mx);   // ror:4
        mx = dpp_maxf<0x128>(mx);   // ror:8
        if (lane == 0) lds_red[s][w] = m_anchor + flog2(fmaxf(mx, 1e-30f));

        // ---- insert + fused shift/rescale (log2->exp2 cancelled via ga^2, rcp) ----
        float nv0 = mySmv * ga * ga;            // exp2(vnew - mcol)
        float rsc = frcp(fmaxf(nv0, 1.0f));     // exp2(mcol - mnew)
        float nv  = fminf(nv0, 1.0f);           // exp2(vnew - mnew)
        mcol = fmaxf(mcol, mac + flog2(mySmv)); // exact-log column anchor update
        // q0's age-32 -> q1's age-33: pick the non-own element (direction-agnostic)
        f32x2 hp  = xchg32(v[15].y);
        float oth = (hp.x == v[15].y) ? hp.y : hp.x;
        float hand = oth * rsc;
        #pragma unroll
        for (int k = 15; k >= 1; --k) {
            v[k].y = v[k].x * rsc;
            v[k].x = v[k - 1].y * rsc;
        }
        v[0].y = v[0].x * rsc;
        v[0].x = (q == 0) ? nv : hand;
        if (t + 1 < T_) m_anchor = m_next;      // keep last-step anchor for loglik
    }

    // ---- loglik: lds_ph[last] holds f16 exp2(alpha_{T-1} - m_anchor) ----
    if (tid < 64) {
        const _Float16* lp = lds_ph[(T_ - 1) & 1];
        float sf = (float)lp[tid] + (float)lp[tid + 64]
                 + (float)lp[tid + 128] + (float)lp[tid + 192];
        #pragma unroll
        for (int off = 1; off < 64; off <<= 1)
            sf += __shfl_xor(sf, off, 64);
        if (tid == 0) out[b] = (m_anchor + flog2(sf)) * LN2;
    }
}

extern "C" void kernel_launch(void* const* d_in, const int* in_sizes, int n_in,
                              void* d_out, int out_size, void* d_ws, size_t ws_size,
                              hipStream_t stream) {
    const float* logB = (const float*)d_in[0];   // [16,2048,256]
    const float* pi   = (const float*)d_in[1];   // [256]
    const float* A    = (const float*)d_in[2];   // [256,256]
    const float* D    = (const float*)d_in[3];   // [256,64]
    float* out = (float*)d_out;
    (void)in_sizes; (void)n_in; (void)d_ws; (void)ws_size; (void)out_size;

    hipLaunchKernelGGL(hsmm_fwd_kernel, dim3(B_), dim3(512), 0, stream,
                       logB, pi, A, D, out);
}